// Round 8
// baseline (531.265 us; speedup 1.0000x reference)
//
#include <hip/hip_runtime.h>

// CNF forward: 8 fixed dopri5 steps x 6 stages, rows independent.
// R13: R12's AGPR pin spilled again (550MB scratch) -> reverted. Base = R11
// (276us, zero spill). Structural change: MM2 becomes SPLIT-K PARTIALS:
// wave Q multiplies only its OWN 64 j (h read from own sH slice, 2 b128,
// NO barrier -- own data) against w2f = W2^T[all 64 douts][own j] (8 frags,
// 32 regs, same count as R9 but arch demand cut: ghv repacked u32, pf tiles
// die at their sPF store -> peak arch ~70-75 < the 84 cap that sank R9).
// Cross-wave sum via sPF[writer][dt] (16KB LDS): 4 b128 writes + 4 reads.
// sW2T (8 stage-invariant b128 reads/stage) deleted. Wide reads/wave-stage
// 22 -> 12. Still 2 barriers/stage (sY, sPF) -- hazard-checked.
// Tripwire: FETCH > 100 MB = arch overflow -> revert to R11 verbatim.

typedef __bf16 bf16x8 __attribute__((ext_vector_type(8)));
typedef __bf16 bf16x4 __attribute__((ext_vector_type(4)));
typedef float  f32x4  __attribute__((ext_vector_type(4)));
typedef unsigned int u32;

#define MFMA16(a, b, c) __builtin_amdgcn_mfma_f32_16x16x32_bf16((a), (b), (c), 0, 0, 0)

__device__ __forceinline__ u32 bfbits(float x) {
    __bf16 b = (__bf16)x;                      // RNE fp32->bf16
    return (u32)__builtin_bit_cast(unsigned short, b);
}
__device__ __forceinline__ float frombits(u32 u16) {
    return __builtin_bit_cast(float, u16 << 16);
}
__device__ __forceinline__ u32 pack2(float lo, float hi) {
    return bfbits(lo) | (bfbits(hi) << 16);
}
__device__ __forceinline__ float fast_tanh(float x) {
    float e = __expf(2.0f * x);
    return 1.0f - 2.0f * __builtin_amdgcn_rcpf(e + 1.0f);
}

extern "C" __global__ void __launch_bounds__(256, 3)
cnf_kernel(const float* __restrict__ Yg, const float* __restrict__ Eg,
           const float* __restrict__ W1g, const float* __restrict__ b1g,
           const float* __restrict__ W2g, const float* __restrict__ b2g,
           float* __restrict__ Og)
{
    // ---- LDS (~28.9 KB; 3 blocks/CU) ----
    __shared__ __align__(16) __bf16 sY[16 * 72];    // y buf [batch][d]
    __shared__ __align__(16) __bf16 sH[16 * 264];   // h buf [batch][j] (own-slice reads only)
    __shared__ __align__(16) float  sPF[4 * 4 * 16 * 16]; // partial f [writer][dt][b][dout']
    __shared__ float sBW[256];                      // per-stage b1 + t*W1_t
    __shared__ __align__(16) float sB2[64];         // b2
    __shared__ float sRedSS[64], sRedLP[64];

    const int tid  = threadIdx.x;
    const int wave = tid >> 6;        // 0..3: wave's slot within the group
    const int lane = tid & 63;
    const int quad = lane >> 4;
    const int l16  = lane & 15;
    const int colb = wave * 16;       // own output-col tile base
    const int jb   = wave * 64;       // own hidden-j base (4 tiles of 16)
    const int row  = blockIdx.x * 16 + l16;   // this lane's batch row

    if (tid < 64) sB2[tid] = b2g[tid];

    // ---------------- e fragments direct from global ----------------
    bf16x8 ae0, ae1;
    {
        f32x4 ea = *(const f32x4*)(Eg + row * 64 + quad * 8);
        f32x4 eb = *(const f32x4*)(Eg + row * 64 + quad * 8 + 4);
        f32x4 ec = *(const f32x4*)(Eg + row * 64 + 32 + quad * 8);
        f32x4 ed = *(const f32x4*)(Eg + row * 64 + 32 + quad * 8 + 4);
        ae0[0]=(__bf16)ea[0]; ae0[1]=(__bf16)ea[1]; ae0[2]=(__bf16)ea[2]; ae0[3]=(__bf16)ea[3];
        ae0[4]=(__bf16)eb[0]; ae0[5]=(__bf16)eb[1]; ae0[6]=(__bf16)eb[2]; ae0[7]=(__bf16)eb[3];
        ae1[0]=(__bf16)ec[0]; ae1[1]=(__bf16)ec[1]; ae1[2]=(__bf16)ec[2]; ae1[3]=(__bf16)ec[3];
        ae1[4]=(__bf16)ed[0]; ae1[5]=(__bf16)ed[1]; ae1[6]=(__bf16)ed[2]; ae1[7]=(__bf16)ed[3];
    }

    // ---------------- W1 fragments direct from global (A-op: [m=j][k=d]) ----
    // w1f[t*2+h][i] = W1^T[j = jb+t*16+l16][d = h*32+quad*8+i] = W1g[d*256 + j]
    bf16x8 w1f[8];
#pragma unroll
    for (int t = 0; t < 4; ++t) {
#pragma unroll
        for (int h = 0; h < 2; ++h) {
            const float* src = W1g + (h * 32 + quad * 8) * 256 + jb + t * 16 + l16;
            bf16x8 f;
#pragma unroll
            for (int i = 0; i < 8; ++i) f[i] = (__bf16)src[i * 256];
            w1f[t * 2 + h] = f;
        }
    }

    // ---------------- ghvp[j][batch] = (gh0 .* v) packed, j=quad*4+rg, b=l16 ----
    u32 ghvp[8];   // [tile*2 + pair], bf16x2 packed
#pragma unroll
    for (int t = 0; t < 4; ++t) {
        f32x4 vacc = {0.f, 0.f, 0.f, 0.f};
        vacc = MFMA16(w1f[t * 2 + 0], ae0, vacc);
        vacc = MFMA16(w1f[t * 2 + 1], ae1, vacc);
        const float* wr = W2g + (jb + t * 16 + l16) * 64;
        f32x4 p0 = *(const f32x4*)(wr + quad * 8);
        f32x4 p1 = *(const f32x4*)(wr + quad * 8 + 4);
        f32x4 p2 = *(const f32x4*)(wr + 32 + quad * 8);
        f32x4 p3 = *(const f32x4*)(wr + 32 + quad * 8 + 4);
        bf16x8 aw0, aw1;
        aw0[0]=(__bf16)p0[0]; aw0[1]=(__bf16)p0[1]; aw0[2]=(__bf16)p0[2]; aw0[3]=(__bf16)p0[3];
        aw0[4]=(__bf16)p1[0]; aw0[5]=(__bf16)p1[1]; aw0[6]=(__bf16)p1[2]; aw0[7]=(__bf16)p1[3];
        aw1[0]=(__bf16)p2[0]; aw1[1]=(__bf16)p2[1]; aw1[2]=(__bf16)p2[2]; aw1[3]=(__bf16)p2[3];
        aw1[4]=(__bf16)p3[0]; aw1[5]=(__bf16)p3[1]; aw1[6]=(__bf16)p3[2]; aw1[7]=(__bf16)p3[3];
        f32x4 gacc = {0.f, 0.f, 0.f, 0.f};
        gacc = MFMA16(aw0, ae0, gacc);
        gacc = MFMA16(aw1, ae1, gacc);
        ghvp[t * 2 + 0] = pack2(gacc[0] * vacc[0], gacc[1] * vacc[1]);
        ghvp[t * 2 + 1] = pack2(gacc[2] * vacc[2], gacc[3] * vacc[3]);
    }

    // ---------------- w2f: W2^T[all 64 douts][OWN j] (A-op: [m=dout][k=j]) ----
    // w2f[dt*2+s][i] = W2^T[dout = dt*16 + l16][j = jb + s*32 + quad*8 + i]
    //               = W2g[(jb + s*32 + quad*8 + i)*64 + dt*16 + l16]
    bf16x8 w2f[8];
#pragma unroll
    for (int dt = 0; dt < 4; ++dt) {
#pragma unroll
        for (int s = 0; s < 2; ++s) {
            const float* src = W2g + (jb + s * 32 + quad * 8) * 64 + dt * 16 + l16;
            bf16x8 f;
#pragma unroll
            for (int i = 0; i < 8; ++i) f[i] = (__bf16)src[i * 64];
            w2f[dt * 2 + s] = f;
        }
    }

    // ---------------- z state (lane layout: batch=l16, d=colb+quad*4+rg) ----
    f32x4 zv = *(const f32x4*)(Yg + row * 64 + colb + quad * 4);
    const float b1r  = b1g[tid];             // own j = tid
    const float w1tr = W1g[64 * 256 + tid];  // W1 time row

    const float dt = 0.125f;
    u32 kp[6][2];     // k_dz bf16x2: [stage][pair], d = colb + quad*4 + {0..3}
    float lpp = 0.f;  // per-lane partial of dlogp (reduced once in epilogue)

#define KV(s, g) frombits(((g) & 1) ? (kp[s][(g)>>1] >> 16) : (kp[s][(g)>>1] & 0xffffu))

#define S1A(g) (0.2f*KV(0,g))
#define S2A(g) (0.075f*KV(0,g) + 0.225f*KV(1,g))
#define S3A(g) ((44.f/45.f)*KV(0,g) + (-56.f/15.f)*KV(1,g) + (32.f/9.f)*KV(2,g))
#define S4A(g) ((19372.f/6561.f)*KV(0,g) + (-25360.f/2187.f)*KV(1,g) + \
                (64448.f/6561.f)*KV(2,g) + (-212.f/729.f)*KV(3,g))
#define S5A(g) ((9017.f/3168.f)*KV(0,g) + (-355.f/33.f)*KV(1,g) + \
                (46732.f/5247.f)*KV(2,g) + (49.f/176.f)*KV(3,g) + (-5103.f/18656.f)*KV(4,g))
#define CBA(g) ((35.f/384.f)*KV(0,g) + (500.f/1113.f)*KV(2,g) + (125.f/192.f)*KV(3,g) + \
                (-2187.f/6784.f)*KV(4,g) + (11.f/84.f)*KV(5,g))

    // matmul-1 tile: ua init = bw (bias in accumulator); h packed b64 to sH.
#define MM1T(t, DODV) { \
    f32x4 ua = *(const f32x4*)(sBW + jb + (t)*16 + quad * 4); \
    ua = MFMA16(w1f[(t)*2 + 0], a10, ua); \
    ua = MFMA16(w1f[(t)*2 + 1], a11, ua); \
    float h0 = fast_tanh(ua[0]), h1 = fast_tanh(ua[1]); \
    float h2 = fast_tanh(ua[2]), h3 = fast_tanh(ua[3]); \
    if (DODV) { \
        u32 g0 = ghvp[(t)*2 + 0], g1 = ghvp[(t)*2 + 1]; \
        dv += frombits(g0 & 0xffffu) * (1.f - h0*h0); \
        dv += frombits(g0 >> 16)     * (1.f - h1*h1); \
        dv += frombits(g1 & 0xffffu) * (1.f - h2*h2); \
        dv += frombits(g1 >> 16)     * (1.f - h3*h3); \
    } \
    bf16x4 hv; hv[0]=(__bf16)h0; hv[1]=(__bf16)h1; hv[2]=(__bf16)h2; hv[3]=(__bf16)h3; \
    *(bf16x4*)(sH + l16 * 264 + jb + (t)*16 + quad * 4) = hv; }

#define STAGE(st, CTI, DTB, DODV, A0, A1, A2, A3) { \
    const float ti = t0 + (CTI) * dt; \
    { \
        bf16x4 yv; \
        yv[0] = (__bf16)(zv[0] + dt * (A0)); \
        yv[1] = (__bf16)(zv[1] + dt * (A1)); \
        yv[2] = (__bf16)(zv[2] + dt * (A2)); \
        yv[3] = (__bf16)(zv[3] + dt * (A3)); \
        *(bf16x4*)(sY + l16 * 72 + colb + quad * 4) = yv; \
    } \
    sBW[tid] = b1r + ti * w1tr; \
    __syncthreads();  /* barrier1: sY ready; sPF(st-1) reads done everywhere */ \
    bf16x8 a10 = *(const bf16x8*)(sY + l16 * 72 + quad * 8); \
    bf16x8 a11 = *(const bf16x8*)(sY + l16 * 72 + 32 + quad * 8); \
    float dv = 0.f; \
    MM1T(0, DODV) MM1T(1, DODV) MM1T(2, DODV) MM1T(3, DODV) \
    /* no barrier: own-slice sH round trip (lgkmcnt only) */ \
    bf16x8 hf0 = *(const bf16x8*)(sH + l16 * 264 + jb + quad * 8); \
    bf16x8 hf1 = *(const bf16x8*)(sH + l16 * 264 + jb + 32 + quad * 8); \
    { \
        f32x4 pf0 = {0.f,0.f,0.f,0.f}, pf1 = {0.f,0.f,0.f,0.f}; \
        pf0 = MFMA16(w2f[0], hf0, pf0);  pf0 = MFMA16(w2f[1], hf1, pf0); \
        pf1 = MFMA16(w2f[2], hf0, pf1);  pf1 = MFMA16(w2f[3], hf1, pf1); \
        *(f32x4*)(sPF + ((wave * 4 + 0) * 16 + l16) * 16 + quad * 4) = pf0; \
        *(f32x4*)(sPF + ((wave * 4 + 1) * 16 + l16) * 16 + quad * 4) = pf1; \
        f32x4 pf2 = {0.f,0.f,0.f,0.f}, pf3 = {0.f,0.f,0.f,0.f}; \
        pf2 = MFMA16(w2f[4], hf0, pf2);  pf2 = MFMA16(w2f[5], hf1, pf2); \
        pf3 = MFMA16(w2f[6], hf0, pf3);  pf3 = MFMA16(w2f[7], hf1, pf3); \
        *(f32x4*)(sPF + ((wave * 4 + 2) * 16 + l16) * 16 + quad * 4) = pf2; \
        *(f32x4*)(sPF + ((wave * 4 + 3) * 16 + l16) * 16 + quad * 4) = pf3; \
    } \
    __syncthreads();  /* barrier2: sPF ready; sY reads done everywhere */ \
    f32x4 fa = *(const f32x4*)(sB2 + colb + quad * 4); \
    fa += *(const f32x4*)(sPF + ((0 * 4 + wave) * 16 + l16) * 16 + quad * 4); \
    fa += *(const f32x4*)(sPF + ((1 * 4 + wave) * 16 + l16) * 16 + quad * 4); \
    fa += *(const f32x4*)(sPF + ((2 * 4 + wave) * 16 + l16) * 16 + quad * 4); \
    fa += *(const f32x4*)(sPF + ((3 * 4 + wave) * 16 + l16) * 16 + quad * 4); \
    kp[st][0] = pack2(fa[0], fa[1]); \
    kp[st][1] = pack2(fa[2], fa[3]); \
    if (DODV) lpp -= (DTB) * dv; }

    for (int step = 0; step < 8; ++step) {
        const float t0 = dt * (float)step;
        STAGE(0, 0.f,     dt*(35.f/384.f),    1, 0.f,    0.f,    0.f,    0.f)
        STAGE(1, 0.2f,    0.f,                0, S1A(0), S1A(1), S1A(2), S1A(3))
        STAGE(2, 0.3f,    dt*(500.f/1113.f),  1, S2A(0), S2A(1), S2A(2), S2A(3))
        STAGE(3, 0.8f,    dt*(125.f/192.f),   1, S3A(0), S3A(1), S3A(2), S3A(3))
        STAGE(4, 8.f/9.f, dt*(-2187.f/6784.f),1, S4A(0), S4A(1), S4A(2), S4A(3))
        STAGE(5, 1.f,     dt*(11.f/84.f),     1, S5A(0), S5A(1), S5A(2), S5A(3))
        zv[0] += dt * CBA(0);
        zv[1] += dt * CBA(1);
        zv[2] += dt * CBA(2);
        zv[3] += dt * CBA(3);
    }

    // ---------------- epilogue ----------------
    *(f32x4*)(Og + row * 64 + colb + quad * 4) = zv;
    float ss = zv[0]*zv[0] + zv[1]*zv[1] + zv[2]*zv[2] + zv[3]*zv[3];
    ss += __shfl_xor(ss, 16);
    ss += __shfl_xor(ss, 32);
    float lp = lpp;                       // deferred quad-reduction (linear)
    lp += __shfl_xor(lp, 16);
    lp += __shfl_xor(lp, 32);
    if (quad == 0) {
        sRedSS[wave * 16 + l16] = ss;
        sRedLP[wave * 16 + l16] = lp;
    }
    __syncthreads();
    if (tid < 16) {
        const float CLOG = -58.8120661f;  // -32*ln(2*pi)
        float sfull = sRedSS[tid] + sRedSS[16 + tid] + sRedSS[32 + tid] + sRedSS[48 + tid];
        float lfull = sRedLP[tid] + sRedLP[16 + tid] + sRedLP[32 + tid] + sRedLP[48 + tid];
        Og[32768 * 64 + blockIdx.x * 16 + tid] = CLOG - 0.5f * sfull - lfull;
    }
}

extern "C" void kernel_launch(void* const* d_in, const int* in_sizes, int n_in,
                              void* d_out, int out_size, void* d_ws, size_t ws_size,
                              hipStream_t stream) {
    const float* Yg  = (const float*)d_in[0];
    const float* Eg  = (const float*)d_in[1];
    const float* W1g = (const float*)d_in[2];  // [65][256]
    const float* b1g = (const float*)d_in[3];
    const float* W2g = (const float*)d_in[4];  // [256][64]
    const float* b2g = (const float*)d_in[5];
    float* Og = (float*)d_out;                 // z (32768*64) then log_px (32768)
    cnf_kernel<<<dim3(2048), dim3(256), 0, stream>>>(Yg, Eg, W1g, b1g, W2g, b2g, Og);
}

// Round 9
// 305.324 us; speedup vs baseline: 1.7400x; 1.7400x over previous
//
#include <hip/hip_runtime.h>

// CNF forward: 8 fixed dopri5 steps x 6 stages, rows independent.
// R14: R13 (split-K) spilled like R12 -> reverted to R11 (276us steady, the
// zero-spill 3-wave/EU config: MM2 weights in LDS). Wall = LDS pipe ~80%
// busy incl. pigeonhole-inherent b128 conflicts; register wall (84-arch cap)
// blocks op-count cuts. This round is SCHEDULING, not structure:
//  * Hoist the stage-invariant sW2T reads (chunks 0-3) + sB2 read to BEFORE
//    barrier2 -- legal (read-only after init; compiler can't hoist LDS loads
//    across __syncthreads itself), overlaps ~120-cyc LDS latency with the
//    barrier convergence window. Chunks 4-7 stay inline (caps live-range
//    growth at ~+20 regs at a low-pressure point; MM1 peak ~80 <= 84).
//  * lp quad-reduction deferred to epilogue (removes 2 ds-pipe shfls x 40
//    stages from the stage chain) -- the safe piece of R12.
// Tripwire: FETCH > 100 MB = spill -> revert to R11 verbatim.

typedef __bf16 bf16x8 __attribute__((ext_vector_type(8)));
typedef __bf16 bf16x4 __attribute__((ext_vector_type(4)));
typedef float  f32x4  __attribute__((ext_vector_type(4)));
typedef unsigned int u32;

#define MFMA16(a, b, c) __builtin_amdgcn_mfma_f32_16x16x32_bf16((a), (b), (c), 0, 0, 0)

__device__ __forceinline__ u32 bfbits(float x) {
    __bf16 b = (__bf16)x;                      // RNE fp32->bf16
    return (u32)__builtin_bit_cast(unsigned short, b);
}
__device__ __forceinline__ float frombits(u32 u16) {
    return __builtin_bit_cast(float, u16 << 16);
}
__device__ __forceinline__ u32 pack2(float lo, float hi) {
    return bfbits(lo) | (bfbits(hi) << 16);
}
__device__ __forceinline__ float fast_tanh(float x) {
    float e = __expf(2.0f * x);
    return 1.0f - 2.0f * __builtin_amdgcn_rcpf(e + 1.0f);
}

extern "C" __global__ void __launch_bounds__(256, 3)
cnf_kernel(const float* __restrict__ Yg, const float* __restrict__ Eg,
           const float* __restrict__ W1g, const float* __restrict__ b1g,
           const float* __restrict__ W2g, const float* __restrict__ b2g,
           float* __restrict__ Og)
{
    // ---- LDS (~46.8 KB; 3 blocks/CU, matching the 12-wave reg cap) ----
    __shared__ __align__(16) __bf16 sW2T[64 * 264]; // W2^T [dout][j], shared by all waves
    __shared__ __align__(16) __bf16 sY[16 * 72];    // y buf [batch][d]
    __shared__ __align__(16) __bf16 sH[16 * 264];   // h buf [batch][j]
    __shared__ float sBW[256];                      // per-stage b1 + t*W1_t
    __shared__ __align__(16) float sB2[64];         // b2
    __shared__ float sRedSS[64], sRedLP[64];

    const int tid  = threadIdx.x;
    const int wave = tid >> 6;        // 0..3: wave's slot within the group
    const int lane = tid & 63;
    const int quad = lane >> 4;
    const int l16  = lane & 15;
    const int colb = wave * 16;       // own output-col tile base
    const int jb   = wave * 64;       // own hidden-j base (4 tiles of 16)
    const int row  = blockIdx.x * 16 + l16;   // this lane's batch row

    if (tid < 64) sB2[tid] = b2g[tid];

    // ---------------- stage W2^T into shared LDS: sW2T[d*264 + j] = W2[j][d] ----
    for (int idx = tid; idx < 256 * 64; idx += 256) {
        int j = idx >> 6, d = idx & 63;
        sW2T[d * 264 + j] = (__bf16)W2g[idx];
    }

    // ---------------- e fragments direct from global ----------------
    // ae: lane (l16=batch, quad) holds e[row][d = quad*8 + i] (+32 for ae1)
    bf16x8 ae0, ae1;
    {
        f32x4 ea = *(const f32x4*)(Eg + row * 64 + quad * 8);
        f32x4 eb = *(const f32x4*)(Eg + row * 64 + quad * 8 + 4);
        f32x4 ec = *(const f32x4*)(Eg + row * 64 + 32 + quad * 8);
        f32x4 ed = *(const f32x4*)(Eg + row * 64 + 32 + quad * 8 + 4);
        ae0[0]=(__bf16)ea[0]; ae0[1]=(__bf16)ea[1]; ae0[2]=(__bf16)ea[2]; ae0[3]=(__bf16)ea[3];
        ae0[4]=(__bf16)eb[0]; ae0[5]=(__bf16)eb[1]; ae0[6]=(__bf16)eb[2]; ae0[7]=(__bf16)eb[3];
        ae1[0]=(__bf16)ec[0]; ae1[1]=(__bf16)ec[1]; ae1[2]=(__bf16)ec[2]; ae1[3]=(__bf16)ec[3];
        ae1[4]=(__bf16)ed[0]; ae1[5]=(__bf16)ed[1]; ae1[6]=(__bf16)ed[2]; ae1[7]=(__bf16)ed[3];
    }

    // ---------------- W1 fragments direct from global (A-op: [m=j][k=d]) ----
    // w1f[t*2+h][i] = W1^T[j = jb+t*16+l16][d = h*32+quad*8+i] = W1g[d*256 + j]
    bf16x8 w1f[8];
#pragma unroll
    for (int t = 0; t < 4; ++t) {
#pragma unroll
        for (int h = 0; h < 2; ++h) {
            const float* src = W1g + (h * 32 + quad * 8) * 256 + jb + t * 16 + l16;
            bf16x8 f;
#pragma unroll
            for (int i = 0; i < 8; ++i) f[i] = (__bf16)src[i * 256];
            w1f[t * 2 + h] = f;
        }
    }

    // ---------------- ghvp[j][batch] = (gh0 .* v) packed, j=quad*4+rg, b=l16 ----
    // v^T = (e@W1a)^T via operand swap (A/B frag layouts match, swap = transpose)
    // gh0^T = W2@e^T: A=W2[m=j][k=d] (contiguous rows of W2g), B=e^T
    u32 ghvp[8];   // [tile*2 + pair], bf16x2 packed
#pragma unroll
    for (int t = 0; t < 4; ++t) {
        f32x4 vacc = {0.f, 0.f, 0.f, 0.f};
        vacc = MFMA16(w1f[t * 2 + 0], ae0, vacc);
        vacc = MFMA16(w1f[t * 2 + 1], ae1, vacc);
        const float* wr = W2g + (jb + t * 16 + l16) * 64;
        f32x4 p0 = *(const f32x4*)(wr + quad * 8);
        f32x4 p1 = *(const f32x4*)(wr + quad * 8 + 4);
        f32x4 p2 = *(const f32x4*)(wr + 32 + quad * 8);
        f32x4 p3 = *(const f32x4*)(wr + 32 + quad * 8 + 4);
        bf16x8 aw0, aw1;
        aw0[0]=(__bf16)p0[0]; aw0[1]=(__bf16)p0[1]; aw0[2]=(__bf16)p0[2]; aw0[3]=(__bf16)p0[3];
        aw0[4]=(__bf16)p1[0]; aw0[5]=(__bf16)p1[1]; aw0[6]=(__bf16)p1[2]; aw0[7]=(__bf16)p1[3];
        aw1[0]=(__bf16)p2[0]; aw1[1]=(__bf16)p2[1]; aw1[2]=(__bf16)p2[2]; aw1[3]=(__bf16)p2[3];
        aw1[4]=(__bf16)p3[0]; aw1[5]=(__bf16)p3[1]; aw1[6]=(__bf16)p3[2]; aw1[7]=(__bf16)p3[3];
        f32x4 gacc = {0.f, 0.f, 0.f, 0.f};
        gacc = MFMA16(aw0, ae0, gacc);
        gacc = MFMA16(aw1, ae1, gacc);
        ghvp[t * 2 + 0] = pack2(gacc[0] * vacc[0], gacc[1] * vacc[1]);
        ghvp[t * 2 + 1] = pack2(gacc[2] * vacc[2], gacc[3] * vacc[3]);
    }

    // ---------------- z state (lane layout: batch=l16, d=colb+quad*4+rg) ----
    f32x4 zv = *(const f32x4*)(Yg + row * 64 + colb + quad * 4);
    const float b1r  = b1g[tid];             // own j = tid
    const float w1tr = W1g[64 * 256 + tid];  // W1 time row

    const float dt = 0.125f;
    u32 kp[6][2];     // k_dz bf16x2: [stage][pair], d = colb + quad*4 + {0..3}
    float lpp = 0.f;  // per-lane partial of dlogp (reduced once in epilogue)

#define KV(s, g) frombits(((g) & 1) ? (kp[s][(g)>>1] >> 16) : (kp[s][(g)>>1] & 0xffffu))

#define S1A(g) (0.2f*KV(0,g))
#define S2A(g) (0.075f*KV(0,g) + 0.225f*KV(1,g))
#define S3A(g) ((44.f/45.f)*KV(0,g) + (-56.f/15.f)*KV(1,g) + (32.f/9.f)*KV(2,g))
#define S4A(g) ((19372.f/6561.f)*KV(0,g) + (-25360.f/2187.f)*KV(1,g) + \
                (64448.f/6561.f)*KV(2,g) + (-212.f/729.f)*KV(3,g))
#define S5A(g) ((9017.f/3168.f)*KV(0,g) + (-355.f/33.f)*KV(1,g) + \
                (46732.f/5247.f)*KV(2,g) + (49.f/176.f)*KV(3,g) + (-5103.f/18656.f)*KV(4,g))
#define CBA(g) ((35.f/384.f)*KV(0,g) + (500.f/1113.f)*KV(2,g) + (125.f/192.f)*KV(3,g) + \
                (-2187.f/6784.f)*KV(4,g) + (11.f/84.f)*KV(5,g))

    // matmul-1 tile: ua init = bw (bias in accumulator); h packed b64 to sH.
#define MM1T(t, DODV) { \
    f32x4 ua = *(const f32x4*)(sBW + jb + (t)*16 + quad * 4); \
    ua = MFMA16(w1f[(t)*2 + 0], a10, ua); \
    ua = MFMA16(w1f[(t)*2 + 1], a11, ua); \
    float h0 = fast_tanh(ua[0]), h1 = fast_tanh(ua[1]); \
    float h2 = fast_tanh(ua[2]), h3 = fast_tanh(ua[3]); \
    if (DODV) { \
        u32 g0 = ghvp[(t)*2 + 0], g1 = ghvp[(t)*2 + 1]; \
        dv += frombits(g0 & 0xffffu) * (1.f - h0*h0); \
        dv += frombits(g0 >> 16)     * (1.f - h1*h1); \
        dv += frombits(g1 & 0xffffu) * (1.f - h2*h2); \
        dv += frombits(g1 >> 16)     * (1.f - h3*h3); \
    } \
    bf16x4 hv; hv[0]=(__bf16)h0; hv[1]=(__bf16)h1; hv[2]=(__bf16)h2; hv[3]=(__bf16)h3; \
    *(bf16x4*)(sH + l16 * 264 + jb + (t)*16 + quad * 4) = hv; }

#define MM2C(c, acc) { \
    bf16x8 hf = *(const bf16x8*)(sH + l16 * 264 + (c)*32 + quad * 8); \
    bf16x8 wf = *(const bf16x8*)(sW2T + (colb + l16) * 264 + (c)*32 + quad * 8); \
    acc = MFMA16(wf, hf, acc); }

#define STAGE(st, CTI, DTB, DODV, A0, A1, A2, A3) { \
    const float ti = t0 + (CTI) * dt; \
    { \
        bf16x4 yv; \
        yv[0] = (__bf16)(zv[0] + dt * (A0)); \
        yv[1] = (__bf16)(zv[1] + dt * (A1)); \
        yv[2] = (__bf16)(zv[2] + dt * (A2)); \
        yv[3] = (__bf16)(zv[3] + dt * (A3)); \
        *(bf16x4*)(sY + l16 * 72 + colb + quad * 4) = yv; \
    } \
    sBW[tid] = b1r + ti * w1tr; \
    __syncthreads();  /* barrier1: sY/sBW ready */ \
    bf16x8 a10 = *(const bf16x8*)(sY + l16 * 72 + quad * 8); \
    bf16x8 a11 = *(const bf16x8*)(sY + l16 * 72 + 32 + quad * 8); \
    float dv = 0.f; \
    MM1T(0, DODV) MM1T(1, DODV) MM1T(2, DODV) MM1T(3, DODV) \
    /* hoist: stage-invariant reads need no barrier; latency overlaps the */ \
    /* barrier2 convergence window (compiler can't move these itself).    */ \
    bf16x8 wfA = *(const bf16x8*)(sW2T + (colb + l16) * 264 + 0*32 + quad * 8); \
    bf16x8 wfB = *(const bf16x8*)(sW2T + (colb + l16) * 264 + 1*32 + quad * 8); \
    bf16x8 wfC = *(const bf16x8*)(sW2T + (colb + l16) * 264 + 2*32 + quad * 8); \
    bf16x8 wfD = *(const bf16x8*)(sW2T + (colb + l16) * 264 + 3*32 + quad * 8); \
    f32x4 fa0 = *(const f32x4*)(sB2 + colb + quad * 4); \
    __syncthreads();  /* barrier2: sH ready */ \
    f32x4 fa1 = {0.f, 0.f, 0.f, 0.f}; \
    { bf16x8 hf = *(const bf16x8*)(sH + l16 * 264 + 0*32 + quad * 8); \
      fa0 = MFMA16(wfA, hf, fa0); } \
    { bf16x8 hf = *(const bf16x8*)(sH + l16 * 264 + 1*32 + quad * 8); \
      fa1 = MFMA16(wfB, hf, fa1); } \
    { bf16x8 hf = *(const bf16x8*)(sH + l16 * 264 + 2*32 + quad * 8); \
      fa0 = MFMA16(wfC, hf, fa0); } \
    { bf16x8 hf = *(const bf16x8*)(sH + l16 * 264 + 3*32 + quad * 8); \
      fa1 = MFMA16(wfD, hf, fa1); } \
    MM2C(4, fa0) MM2C(5, fa1) MM2C(6, fa0) MM2C(7, fa1) \
    f32x4 fa = fa0 + fa1; \
    kp[st][0] = pack2(fa[0], fa[1]); \
    kp[st][1] = pack2(fa[2], fa[3]); \
    if (DODV) lpp -= (DTB) * dv; }

    for (int step = 0; step < 8; ++step) {
        const float t0 = dt * (float)step;
        STAGE(0, 0.f,     dt*(35.f/384.f),    1, 0.f,    0.f,    0.f,    0.f)
        STAGE(1, 0.2f,    0.f,                0, S1A(0), S1A(1), S1A(2), S1A(3))
        STAGE(2, 0.3f,    dt*(500.f/1113.f),  1, S2A(0), S2A(1), S2A(2), S2A(3))
        STAGE(3, 0.8f,    dt*(125.f/192.f),   1, S3A(0), S3A(1), S3A(2), S3A(3))
        STAGE(4, 8.f/9.f, dt*(-2187.f/6784.f),1, S4A(0), S4A(1), S4A(2), S4A(3))
        STAGE(5, 1.f,     dt*(11.f/84.f),     1, S5A(0), S5A(1), S5A(2), S5A(3))
        zv[0] += dt * CBA(0);
        zv[1] += dt * CBA(1);
        zv[2] += dt * CBA(2);
        zv[3] += dt * CBA(3);
    }

    // ---------------- epilogue ----------------
    *(f32x4*)(Og + row * 64 + colb + quad * 4) = zv;
    float ss = zv[0]*zv[0] + zv[1]*zv[1] + zv[2]*zv[2] + zv[3]*zv[3];
    ss += __shfl_xor(ss, 16);
    ss += __shfl_xor(ss, 32);
    float lp = lpp;                       // deferred quad-reduction (linear)
    lp += __shfl_xor(lp, 16);
    lp += __shfl_xor(lp, 32);
    if (quad == 0) {
        sRedSS[wave * 16 + l16] = ss;
        sRedLP[wave * 16 + l16] = lp;
    }
    __syncthreads();
    if (tid < 16) {
        const float CLOG = -58.8120661f;  // -32*ln(2*pi)
        float sfull = sRedSS[tid] + sRedSS[16 + tid] + sRedSS[32 + tid] + sRedSS[48 + tid];
        float lfull = sRedLP[tid] + sRedLP[16 + tid] + sRedLP[32 + tid] + sRedLP[48 + tid];
        Og[32768 * 64 + blockIdx.x * 16 + tid] = CLOG - 0.5f * sfull - lfull;
    }
}

extern "C" void kernel_launch(void* const* d_in, const int* in_sizes, int n_in,
                              void* d_out, int out_size, void* d_ws, size_t ws_size,
                              hipStream_t stream) {
    const float* Yg  = (const float*)d_in[0];
    const float* Eg  = (const float*)d_in[1];
    const float* W1g = (const float*)d_in[2];  // [65][256]
    const float* b1g = (const float*)d_in[3];
    const float* W2g = (const float*)d_in[4];  // [256][64]
    const float* b2g = (const float*)d_in[5];
    float* Og = (float*)d_out;                 // z (32768*64) then log_px (32768)
    cnf_kernel<<<dim3(2048), dim3(256), 0, stream>>>(Yg, Eg, W1g, b1g, W2g, b2g, Og);
}

// Round 10
// 275.671 us; speedup vs baseline: 1.9272x; 1.1076x over previous
//
#include <hip/hip_runtime.h>

// CNF forward: 8 fixed dopri5 steps x 6 stages, rows independent.
// R15: R14 (271us steady) is scheduling-exhausted; wall = LDS pipe ~72%
// (incl. 8KB/wave-stage of stage-invariant sW2T re-reads forced by the
// 84-arch-reg cap at 3 waves/EU). Untried corner: back to the 2-waves/EU
// tier (256-reg budget -- the regime where R5 provably held BOTH weight
// sets in registers spill-free) + DUAL-TILE ILP to fix R5's parallelism
// deficit: each 4-wave block runs TWO 16-row tiles in lock-step.
//  * per CU: 2 blocks x 32 rows = 64 concurrent rows (R14: 48, R5: 32)
//  * w1f+w2f in regs (acc half, 64) -> sW2T deleted: -30% LDS bytes/row
//  * tiles share sBW + the 2 barriers (barrier cost/row halved); post-
//    barrier latency filled by the other tile's independent MFMA chains
//  * arch ~110 + acc 64 = ~175 <= 256: no spill by budget margin
// Tripwire: FETCH > 100 MB = spill -> revert to R14.

typedef __bf16 bf16x8 __attribute__((ext_vector_type(8)));
typedef __bf16 bf16x4 __attribute__((ext_vector_type(4)));
typedef float  f32x4  __attribute__((ext_vector_type(4)));
typedef unsigned int u32;

#define MFMA16(a, b, c) __builtin_amdgcn_mfma_f32_16x16x32_bf16((a), (b), (c), 0, 0, 0)

__device__ __forceinline__ u32 bfbits(float x) {
    __bf16 b = (__bf16)x;                      // RNE fp32->bf16
    return (u32)__builtin_bit_cast(unsigned short, b);
}
__device__ __forceinline__ float frombits(u32 u16) {
    return __builtin_bit_cast(float, u16 << 16);
}
__device__ __forceinline__ u32 pack2(float lo, float hi) {
    return bfbits(lo) | (bfbits(hi) << 16);
}
__device__ __forceinline__ float fast_tanh(float x) {
    float e = __expf(2.0f * x);
    return 1.0f - 2.0f * __builtin_amdgcn_rcpf(e + 1.0f);
}
__device__ __forceinline__ bf16x8 cvt8(f32x4 a, f32x4 b) {
    bf16x8 r;
#pragma unroll
    for (int i = 0; i < 4; ++i) { r[i] = (__bf16)a[i]; r[4 + i] = (__bf16)b[i]; }
    return r;
}

extern "C" __global__ void __launch_bounds__(256, 2)
cnf_kernel(const float* __restrict__ Yg, const float* __restrict__ Eg,
           const float* __restrict__ W1g, const float* __restrict__ b1g,
           const float* __restrict__ W2g, const float* __restrict__ b2g,
           float* __restrict__ Og)
{
    // ---- LDS (~23.5 KB; 2 blocks/CU at 2 waves/EU) ----
    __shared__ __align__(16) __bf16 sYA[16 * 72], sYB[16 * 72];
    __shared__ __align__(16) __bf16 sHA[16 * 264], sHB[16 * 264];
    __shared__ float sBW[256];                      // per-stage b1 + t*W1_t (shared by tiles)
    __shared__ float sRedSS[128], sRedLP[128];

    const int tid  = threadIdx.x;
    const int wave = tid >> 6;        // 0..3
    const int lane = tid & 63;
    const int quad = lane >> 4;
    const int l16  = lane & 15;
    const int colb = wave * 16;       // own output-col tile base
    const int jb   = wave * 64;       // own hidden-j base
    const int rowA = blockIdx.x * 32 + l16;   // tile A batch row
    const int rowB = rowA + 16;               // tile B batch row

    // ---------------- e fragments (both tiles) ----------------
    bf16x8 aeA0, aeA1, aeB0, aeB1;
    {
        const float* eA = Eg + rowA * 64;
        const float* eB = Eg + rowB * 64;
        aeA0 = cvt8(*(const f32x4*)(eA + quad * 8),      *(const f32x4*)(eA + quad * 8 + 4));
        aeA1 = cvt8(*(const f32x4*)(eA + 32 + quad * 8), *(const f32x4*)(eA + 32 + quad * 8 + 4));
        aeB0 = cvt8(*(const f32x4*)(eB + quad * 8),      *(const f32x4*)(eB + quad * 8 + 4));
        aeB1 = cvt8(*(const f32x4*)(eB + 32 + quad * 8), *(const f32x4*)(eB + 32 + quad * 8 + 4));
    }

    // ---------------- W1 fragments direct from global (A-op: [m=j][k=d]) ----
    bf16x8 w1f[8];
#pragma unroll
    for (int t = 0; t < 4; ++t) {
#pragma unroll
        for (int h = 0; h < 2; ++h) {
            const float* src = W1g + (h * 32 + quad * 8) * 256 + jb + t * 16 + l16;
            bf16x8 f;
#pragma unroll
            for (int i = 0; i < 8; ++i) f[i] = (__bf16)src[i * 256];
            w1f[t * 2 + h] = f;
        }
    }

    // ---------------- ghvp per tile: (gh0 .* v), j=quad*4+rg, b=l16 ----
    // v^T = (e@W1a)^T via operand swap; gh0^T = W2 @ e^T (aw rows shared by tiles)
    u32 ghvpA[8], ghvpB[8];
#pragma unroll
    for (int t = 0; t < 4; ++t) {
        const float* wr = W2g + (jb + t * 16 + l16) * 64;
        bf16x8 aw0 = cvt8(*(const f32x4*)(wr + quad * 8),      *(const f32x4*)(wr + quad * 8 + 4));
        bf16x8 aw1 = cvt8(*(const f32x4*)(wr + 32 + quad * 8), *(const f32x4*)(wr + 32 + quad * 8 + 4));
        f32x4 vA = {0.f,0.f,0.f,0.f}, vB = {0.f,0.f,0.f,0.f};
        f32x4 gA = {0.f,0.f,0.f,0.f}, gB = {0.f,0.f,0.f,0.f};
        vA = MFMA16(w1f[t * 2 + 0], aeA0, vA);  vA = MFMA16(w1f[t * 2 + 1], aeA1, vA);
        vB = MFMA16(w1f[t * 2 + 0], aeB0, vB);  vB = MFMA16(w1f[t * 2 + 1], aeB1, vB);
        gA = MFMA16(aw0, aeA0, gA);             gA = MFMA16(aw1, aeA1, gA);
        gB = MFMA16(aw0, aeB0, gB);             gB = MFMA16(aw1, aeB1, gB);
        ghvpA[t * 2 + 0] = pack2(gA[0] * vA[0], gA[1] * vA[1]);
        ghvpA[t * 2 + 1] = pack2(gA[2] * vA[2], gA[3] * vA[3]);
        ghvpB[t * 2 + 0] = pack2(gB[0] * vB[0], gB[1] * vB[1]);
        ghvpB[t * 2 + 1] = pack2(gB[2] * vB[2], gB[3] * vB[3]);
    }

    // ---------------- W2^T fragments direct from global (A-op: [m=dout][k=j]) ----
    bf16x8 w2f[8];
#pragma unroll
    for (int c = 0; c < 8; ++c) {
        const float* src = W2g + (c * 32 + quad * 8) * 64 + colb + l16;
        bf16x8 f;
#pragma unroll
        for (int i = 0; i < 8; ++i) f[i] = (__bf16)src[i * 64];
        w2f[c] = f;
    }

    // ---------------- state (lane layout: batch=l16, d=colb+quad*4+rg) ----
    f32x4 zvA = *(const f32x4*)(Yg + rowA * 64 + colb + quad * 4);
    f32x4 zvB = *(const f32x4*)(Yg + rowB * 64 + colb + quad * 4);
    f32x4 bb2 = *(const f32x4*)(b2g + colb + quad * 4);
    const float b1r  = b1g[tid];             // own j = tid
    const float w1tr = W1g[64 * 256 + tid];  // W1 time row

    const float dt = 0.125f;
    u32 kpA[6][2], kpB[6][2];   // k_dz bf16x2 per tile
    float lppA = 0.f, lppB = 0.f;

#define KV(arr, s, g) frombits(((g) & 1) ? (arr[s][(g)>>1] >> 16) : (arr[s][(g)>>1] & 0xffffu))
#define S0X(arr, g) 0.f
#define S1X(arr, g) (0.2f*KV(arr,0,g))
#define S2X(arr, g) (0.075f*KV(arr,0,g) + 0.225f*KV(arr,1,g))
#define S3X(arr, g) ((44.f/45.f)*KV(arr,0,g) + (-56.f/15.f)*KV(arr,1,g) + (32.f/9.f)*KV(arr,2,g))
#define S4X(arr, g) ((19372.f/6561.f)*KV(arr,0,g) + (-25360.f/2187.f)*KV(arr,1,g) + \
                     (64448.f/6561.f)*KV(arr,2,g) + (-212.f/729.f)*KV(arr,3,g))
#define S5X(arr, g) ((9017.f/3168.f)*KV(arr,0,g) + (-355.f/33.f)*KV(arr,1,g) + \
                     (46732.f/5247.f)*KV(arr,2,g) + (49.f/176.f)*KV(arr,3,g) + \
                     (-5103.f/18656.f)*KV(arr,4,g))
#define CBX(arr, g) ((35.f/384.f)*KV(arr,0,g) + (500.f/1113.f)*KV(arr,2,g) + \
                     (125.f/192.f)*KV(arr,3,g) + (-2187.f/6784.f)*KV(arr,4,g) + \
                     (11.f/84.f)*KV(arr,5,g))

    // matmul-1 tile (per data-tile S, j-tile t)
#define MM1T(S, t, DODV) { \
    f32x4 ua = *(const f32x4*)(sBW + jb + (t)*16 + quad * 4); \
    ua = MFMA16(w1f[(t)*2 + 0], a10##S, ua); \
    ua = MFMA16(w1f[(t)*2 + 1], a11##S, ua); \
    float h0 = fast_tanh(ua[0]), h1 = fast_tanh(ua[1]); \
    float h2 = fast_tanh(ua[2]), h3 = fast_tanh(ua[3]); \
    if (DODV) { \
        u32 g0 = ghvp##S[(t)*2 + 0], g1 = ghvp##S[(t)*2 + 1]; \
        dv##S += frombits(g0 & 0xffffu) * (1.f - h0*h0); \
        dv##S += frombits(g0 >> 16)     * (1.f - h1*h1); \
        dv##S += frombits(g1 & 0xffffu) * (1.f - h2*h2); \
        dv##S += frombits(g1 >> 16)     * (1.f - h3*h3); \
    } \
    bf16x4 hv; hv[0]=(__bf16)h0; hv[1]=(__bf16)h1; hv[2]=(__bf16)h2; hv[3]=(__bf16)h3; \
    *(bf16x4*)(sH##S + l16 * 264 + jb + (t)*16 + quad * 4) = hv; }

#define MM2C(S, c, acc) { \
    bf16x8 hf = *(const bf16x8*)(sH##S + l16 * 264 + (c)*32 + quad * 8); \
    acc = MFMA16(w2f[c], hf, acc); }

#define STAGE(st, CTI, DTB, DODV, SX) { \
    const float ti = t0 + (CTI) * dt; \
    { bf16x4 yv; \
      yv[0] = (__bf16)(zvA[0] + dt * (SX(kpA,0))); \
      yv[1] = (__bf16)(zvA[1] + dt * (SX(kpA,1))); \
      yv[2] = (__bf16)(zvA[2] + dt * (SX(kpA,2))); \
      yv[3] = (__bf16)(zvA[3] + dt * (SX(kpA,3))); \
      *(bf16x4*)(sYA + l16 * 72 + colb + quad * 4) = yv; } \
    { bf16x4 yv; \
      yv[0] = (__bf16)(zvB[0] + dt * (SX(kpB,0))); \
      yv[1] = (__bf16)(zvB[1] + dt * (SX(kpB,1))); \
      yv[2] = (__bf16)(zvB[2] + dt * (SX(kpB,2))); \
      yv[3] = (__bf16)(zvB[3] + dt * (SX(kpB,3))); \
      *(bf16x4*)(sYB + l16 * 72 + colb + quad * 4) = yv; } \
    sBW[tid] = b1r + ti * w1tr; \
    __syncthreads();  /* barrier1: sY*/ \
    bf16x8 a10A = *(const bf16x8*)(sYA + l16 * 72 + quad * 8); \
    bf16x8 a11A = *(const bf16x8*)(sYA + l16 * 72 + 32 + quad * 8); \
    bf16x8 a10B = *(const bf16x8*)(sYB + l16 * 72 + quad * 8); \
    bf16x8 a11B = *(const bf16x8*)(sYB + l16 * 72 + 32 + quad * 8); \
    float dvA = 0.f, dvB = 0.f; \
    MM1T(A,0,DODV) MM1T(B,0,DODV) MM1T(A,1,DODV) MM1T(B,1,DODV) \
    MM1T(A,2,DODV) MM1T(B,2,DODV) MM1T(A,3,DODV) MM1T(B,3,DODV) \
    __syncthreads();  /* barrier2: sH */ \
    f32x4 faA0 = bb2, faA1 = {0.f,0.f,0.f,0.f}; \
    f32x4 faB0 = bb2, faB1 = {0.f,0.f,0.f,0.f}; \
    MM2C(A,0,faA0) MM2C(B,0,faB0) MM2C(A,1,faA1) MM2C(B,1,faB1) \
    MM2C(A,2,faA0) MM2C(B,2,faB0) MM2C(A,3,faA1) MM2C(B,3,faB1) \
    MM2C(A,4,faA0) MM2C(B,4,faB0) MM2C(A,5,faA1) MM2C(B,5,faB1) \
    MM2C(A,6,faA0) MM2C(B,6,faB0) MM2C(A,7,faA1) MM2C(B,7,faB1) \
    f32x4 faA = faA0 + faA1, faB = faB0 + faB1; \
    kpA[st][0] = pack2(faA[0], faA[1]);  kpA[st][1] = pack2(faA[2], faA[3]); \
    kpB[st][0] = pack2(faB[0], faB[1]);  kpB[st][1] = pack2(faB[2], faB[3]); \
    if (DODV) { lppA -= (DTB) * dvA; lppB -= (DTB) * dvB; } }

    for (int step = 0; step < 8; ++step) {
        const float t0 = dt * (float)step;
        STAGE(0, 0.f,     dt*(35.f/384.f),    1, S0X)
        STAGE(1, 0.2f,    0.f,                0, S1X)
        STAGE(2, 0.3f,    dt*(500.f/1113.f),  1, S2X)
        STAGE(3, 0.8f,    dt*(125.f/192.f),   1, S3X)
        STAGE(4, 8.f/9.f, dt*(-2187.f/6784.f),1, S4X)
        STAGE(5, 1.f,     dt*(11.f/84.f),     1, S5X)
        zvA[0] += dt * CBX(kpA,0);  zvA[1] += dt * CBX(kpA,1);
        zvA[2] += dt * CBX(kpA,2);  zvA[3] += dt * CBX(kpA,3);
        zvB[0] += dt * CBX(kpB,0);  zvB[1] += dt * CBX(kpB,1);
        zvB[2] += dt * CBX(kpB,2);  zvB[3] += dt * CBX(kpB,3);
    }

    // ---------------- epilogue ----------------
    *(f32x4*)(Og + rowA * 64 + colb + quad * 4) = zvA;
    *(f32x4*)(Og + rowB * 64 + colb + quad * 4) = zvB;
    float ssA = zvA[0]*zvA[0] + zvA[1]*zvA[1] + zvA[2]*zvA[2] + zvA[3]*zvA[3];
    float ssB = zvB[0]*zvB[0] + zvB[1]*zvB[1] + zvB[2]*zvB[2] + zvB[3]*zvB[3];
    ssA += __shfl_xor(ssA, 16);  ssA += __shfl_xor(ssA, 32);
    ssB += __shfl_xor(ssB, 16);  ssB += __shfl_xor(ssB, 32);
    float lpA = lppA;  lpA += __shfl_xor(lpA, 16);  lpA += __shfl_xor(lpA, 32);
    float lpB = lppB;  lpB += __shfl_xor(lpB, 16);  lpB += __shfl_xor(lpB, 32);
    if (quad == 0) {
        sRedSS[wave * 16 + l16] = ssA;       sRedLP[wave * 16 + l16] = lpA;
        sRedSS[64 + wave * 16 + l16] = ssB;  sRedLP[64 + wave * 16 + l16] = lpB;
    }
    __syncthreads();
    if (tid < 32) {
        const float CLOG = -58.8120661f;  // -32*ln(2*pi)
        int half = tid >> 4, r = tid & 15, base = half * 64;
        float sfull = sRedSS[base + r] + sRedSS[base + 16 + r]
                    + sRedSS[base + 32 + r] + sRedSS[base + 48 + r];
        float lfull = sRedLP[base + r] + sRedLP[base + 16 + r]
                    + sRedLP[base + 32 + r] + sRedLP[base + 48 + r];
        Og[32768 * 64 + blockIdx.x * 32 + half * 16 + r] = CLOG - 0.5f * sfull - lfull;
    }
}

extern "C" void kernel_launch(void* const* d_in, const int* in_sizes, int n_in,
                              void* d_out, int out_size, void* d_ws, size_t ws_size,
                              hipStream_t stream) {
    const float* Yg  = (const float*)d_in[0];
    const float* Eg  = (const float*)d_in[1];
    const float* W1g = (const float*)d_in[2];  // [65][256]
    const float* b1g = (const float*)d_in[3];
    const float* W2g = (const float*)d_in[4];  // [256][64]
    const float* b2g = (const float*)d_in[5];
    float* Og = (float*)d_out;                 // z (32768*64) then log_px (32768)
    cnf_kernel<<<dim3(1024), dim3(256), 0, stream>>>(Yg, Eg, W1g, b1g, W2g, b2g, Og);
}

// Round 11
// 269.590 us; speedup vs baseline: 1.9706x; 1.0226x over previous
//
#include <hip/hip_runtime.h>

// CNF forward: 8 fixed dopri5 steps x 6 stages, rows independent.
// R16: R15 (dual-tile, 2 waves/EU, weights in regs) hit 240us steady --
// LDS demoted (conflicts -40%), now VALU-issue + dependency-latency bound
// (VALUBusy 59% @ 2 waves/SIMD). The bf16 k-value packing (a register trick
// from the 84-reg era) costs ~100 VALU/stage of pack2/lshl AND sits on the
// inter-stage critical path (MM2 -> pack -> unpack -> SX fma -> y store).
// At the 256-reg budget there's headroom: kp -> f32 kf[6][4] (+24 regs),
// ghv -> f32 (+16 regs); ~232 total <= 256, occupancy unchanged.
// Tripwire: FETCH > 100 MB = spill -> revert to R15.

typedef __bf16 bf16x8 __attribute__((ext_vector_type(8)));
typedef __bf16 bf16x4 __attribute__((ext_vector_type(4)));
typedef float  f32x4  __attribute__((ext_vector_type(4)));
typedef unsigned int u32;

#define MFMA16(a, b, c) __builtin_amdgcn_mfma_f32_16x16x32_bf16((a), (b), (c), 0, 0, 0)

__device__ __forceinline__ float fast_tanh(float x) {
    float e = __expf(2.0f * x);
    return 1.0f - 2.0f * __builtin_amdgcn_rcpf(e + 1.0f);
}
__device__ __forceinline__ bf16x8 cvt8(f32x4 a, f32x4 b) {
    bf16x8 r;
#pragma unroll
    for (int i = 0; i < 4; ++i) { r[i] = (__bf16)a[i]; r[4 + i] = (__bf16)b[i]; }
    return r;
}

extern "C" __global__ void __launch_bounds__(256, 2)
cnf_kernel(const float* __restrict__ Yg, const float* __restrict__ Eg,
           const float* __restrict__ W1g, const float* __restrict__ b1g,
           const float* __restrict__ W2g, const float* __restrict__ b2g,
           float* __restrict__ Og)
{
    // ---- LDS (~23.5 KB; 2 blocks/CU at 2 waves/EU) ----
    __shared__ __align__(16) __bf16 sYA[16 * 72], sYB[16 * 72];
    __shared__ __align__(16) __bf16 sHA[16 * 264], sHB[16 * 264];
    __shared__ float sBW[256];                      // per-stage b1 + t*W1_t (shared by tiles)
    __shared__ float sRedSS[128], sRedLP[128];

    const int tid  = threadIdx.x;
    const int wave = tid >> 6;        // 0..3
    const int lane = tid & 63;
    const int quad = lane >> 4;
    const int l16  = lane & 15;
    const int colb = wave * 16;       // own output-col tile base
    const int jb   = wave * 64;       // own hidden-j base
    const int rowA = blockIdx.x * 32 + l16;   // tile A batch row
    const int rowB = rowA + 16;               // tile B batch row

    // ---------------- e fragments (both tiles) ----------------
    bf16x8 aeA0, aeA1, aeB0, aeB1;
    {
        const float* eA = Eg + rowA * 64;
        const float* eB = Eg + rowB * 64;
        aeA0 = cvt8(*(const f32x4*)(eA + quad * 8),      *(const f32x4*)(eA + quad * 8 + 4));
        aeA1 = cvt8(*(const f32x4*)(eA + 32 + quad * 8), *(const f32x4*)(eA + 32 + quad * 8 + 4));
        aeB0 = cvt8(*(const f32x4*)(eB + quad * 8),      *(const f32x4*)(eB + quad * 8 + 4));
        aeB1 = cvt8(*(const f32x4*)(eB + 32 + quad * 8), *(const f32x4*)(eB + 32 + quad * 8 + 4));
    }

    // ---------------- W1 fragments direct from global (A-op: [m=j][k=d]) ----
    bf16x8 w1f[8];
#pragma unroll
    for (int t = 0; t < 4; ++t) {
#pragma unroll
        for (int h = 0; h < 2; ++h) {
            const float* src = W1g + (h * 32 + quad * 8) * 256 + jb + t * 16 + l16;
            bf16x8 f;
#pragma unroll
            for (int i = 0; i < 8; ++i) f[i] = (__bf16)src[i * 256];
            w1f[t * 2 + h] = f;
        }
    }

    // ---------------- ghf per tile: (gh0 .* v) f32, j=quad*4+rg, b=l16 ----
    // v^T = (e@W1a)^T via operand swap; gh0^T = W2 @ e^T (aw rows shared by tiles)
    float ghfA[16], ghfB[16];
#pragma unroll
    for (int t = 0; t < 4; ++t) {
        const float* wr = W2g + (jb + t * 16 + l16) * 64;
        bf16x8 aw0 = cvt8(*(const f32x4*)(wr + quad * 8),      *(const f32x4*)(wr + quad * 8 + 4));
        bf16x8 aw1 = cvt8(*(const f32x4*)(wr + 32 + quad * 8), *(const f32x4*)(wr + 32 + quad * 8 + 4));
        f32x4 vA = {0.f,0.f,0.f,0.f}, vB = {0.f,0.f,0.f,0.f};
        f32x4 gA = {0.f,0.f,0.f,0.f}, gB = {0.f,0.f,0.f,0.f};
        vA = MFMA16(w1f[t * 2 + 0], aeA0, vA);  vA = MFMA16(w1f[t * 2 + 1], aeA1, vA);
        vB = MFMA16(w1f[t * 2 + 0], aeB0, vB);  vB = MFMA16(w1f[t * 2 + 1], aeB1, vB);
        gA = MFMA16(aw0, aeA0, gA);             gA = MFMA16(aw1, aeA1, gA);
        gB = MFMA16(aw0, aeB0, gB);             gB = MFMA16(aw1, aeB1, gB);
#pragma unroll
        for (int i = 0; i < 4; ++i) {
            ghfA[t * 4 + i] = gA[i] * vA[i];
            ghfB[t * 4 + i] = gB[i] * vB[i];
        }
    }

    // ---------------- W2^T fragments direct from global (A-op: [m=dout][k=j]) ----
    bf16x8 w2f[8];
#pragma unroll
    for (int c = 0; c < 8; ++c) {
        const float* src = W2g + (c * 32 + quad * 8) * 64 + colb + l16;
        bf16x8 f;
#pragma unroll
        for (int i = 0; i < 8; ++i) f[i] = (__bf16)src[i * 64];
        w2f[c] = f;
    }

    // ---------------- state (lane layout: batch=l16, d=colb+quad*4+rg) ----
    f32x4 zvA = *(const f32x4*)(Yg + rowA * 64 + colb + quad * 4);
    f32x4 zvB = *(const f32x4*)(Yg + rowB * 64 + colb + quad * 4);
    f32x4 bb2 = *(const f32x4*)(b2g + colb + quad * 4);
    const float b1r  = b1g[tid];             // own j = tid
    const float w1tr = W1g[64 * 256 + tid];  // W1 time row

    const float dt = 0.125f;
    float kfA[6][4], kfB[6][4];   // k_dz in raw f32 (no pack/unpack on the chain)
    float lppA = 0.f, lppB = 0.f;

#define S0X(arr, g) 0.f
#define S1X(arr, g) (0.2f*arr[0][g])
#define S2X(arr, g) (0.075f*arr[0][g] + 0.225f*arr[1][g])
#define S3X(arr, g) ((44.f/45.f)*arr[0][g] + (-56.f/15.f)*arr[1][g] + (32.f/9.f)*arr[2][g])
#define S4X(arr, g) ((19372.f/6561.f)*arr[0][g] + (-25360.f/2187.f)*arr[1][g] + \
                     (64448.f/6561.f)*arr[2][g] + (-212.f/729.f)*arr[3][g])
#define S5X(arr, g) ((9017.f/3168.f)*arr[0][g] + (-355.f/33.f)*arr[1][g] + \
                     (46732.f/5247.f)*arr[2][g] + (49.f/176.f)*arr[3][g] + \
                     (-5103.f/18656.f)*arr[4][g])
#define CBX(arr, g) ((35.f/384.f)*arr[0][g] + (500.f/1113.f)*arr[2][g] + \
                     (125.f/192.f)*arr[3][g] + (-2187.f/6784.f)*arr[4][g] + \
                     (11.f/84.f)*arr[5][g])

    // matmul-1 tile (per data-tile S, j-tile t)
#define MM1T(S, t, DODV) { \
    f32x4 ua = *(const f32x4*)(sBW + jb + (t)*16 + quad * 4); \
    ua = MFMA16(w1f[(t)*2 + 0], a10##S, ua); \
    ua = MFMA16(w1f[(t)*2 + 1], a11##S, ua); \
    float h0 = fast_tanh(ua[0]), h1 = fast_tanh(ua[1]); \
    float h2 = fast_tanh(ua[2]), h3 = fast_tanh(ua[3]); \
    if (DODV) { \
        dv##S += ghf##S[(t)*4 + 0] * (1.f - h0*h0); \
        dv##S += ghf##S[(t)*4 + 1] * (1.f - h1*h1); \
        dv##S += ghf##S[(t)*4 + 2] * (1.f - h2*h2); \
        dv##S += ghf##S[(t)*4 + 3] * (1.f - h3*h3); \
    } \
    bf16x4 hv; hv[0]=(__bf16)h0; hv[1]=(__bf16)h1; hv[2]=(__bf16)h2; hv[3]=(__bf16)h3; \
    *(bf16x4*)(sH##S + l16 * 264 + jb + (t)*16 + quad * 4) = hv; }

#define MM2C(S, c, acc) { \
    bf16x8 hf = *(const bf16x8*)(sH##S + l16 * 264 + (c)*32 + quad * 8); \
    acc = MFMA16(w2f[c], hf, acc); }

#define STAGE(st, CTI, DTB, DODV, SX) { \
    const float ti = t0 + (CTI) * dt; \
    { bf16x4 yv; \
      yv[0] = (__bf16)(zvA[0] + dt * (SX(kfA,0))); \
      yv[1] = (__bf16)(zvA[1] + dt * (SX(kfA,1))); \
      yv[2] = (__bf16)(zvA[2] + dt * (SX(kfA,2))); \
      yv[3] = (__bf16)(zvA[3] + dt * (SX(kfA,3))); \
      *(bf16x4*)(sYA + l16 * 72 + colb + quad * 4) = yv; } \
    { bf16x4 yv; \
      yv[0] = (__bf16)(zvB[0] + dt * (SX(kfB,0))); \
      yv[1] = (__bf16)(zvB[1] + dt * (SX(kfB,1))); \
      yv[2] = (__bf16)(zvB[2] + dt * (SX(kfB,2))); \
      yv[3] = (__bf16)(zvB[3] + dt * (SX(kfB,3))); \
      *(bf16x4*)(sYB + l16 * 72 + colb + quad * 4) = yv; } \
    sBW[tid] = b1r + ti * w1tr; \
    __syncthreads();  /* barrier1: sY/sBW */ \
    bf16x8 a10A = *(const bf16x8*)(sYA + l16 * 72 + quad * 8); \
    bf16x8 a11A = *(const bf16x8*)(sYA + l16 * 72 + 32 + quad * 8); \
    bf16x8 a10B = *(const bf16x8*)(sYB + l16 * 72 + quad * 8); \
    bf16x8 a11B = *(const bf16x8*)(sYB + l16 * 72 + 32 + quad * 8); \
    float dvA = 0.f, dvB = 0.f; \
    MM1T(A,0,DODV) MM1T(B,0,DODV) MM1T(A,1,DODV) MM1T(B,1,DODV) \
    MM1T(A,2,DODV) MM1T(B,2,DODV) MM1T(A,3,DODV) MM1T(B,3,DODV) \
    __syncthreads();  /* barrier2: sH */ \
    f32x4 faA0 = bb2, faA1 = {0.f,0.f,0.f,0.f}; \
    f32x4 faB0 = bb2, faB1 = {0.f,0.f,0.f,0.f}; \
    MM2C(A,0,faA0) MM2C(B,0,faB0) MM2C(A,1,faA1) MM2C(B,1,faB1) \
    MM2C(A,2,faA0) MM2C(B,2,faB0) MM2C(A,3,faA1) MM2C(B,3,faB1) \
    MM2C(A,4,faA0) MM2C(B,4,faB0) MM2C(A,5,faA1) MM2C(B,5,faB1) \
    MM2C(A,6,faA0) MM2C(B,6,faB0) MM2C(A,7,faA1) MM2C(B,7,faB1) \
    f32x4 faA = faA0 + faA1, faB = faB0 + faB1; \
    kfA[st][0] = faA[0]; kfA[st][1] = faA[1]; kfA[st][2] = faA[2]; kfA[st][3] = faA[3]; \
    kfB[st][0] = faB[0]; kfB[st][1] = faB[1]; kfB[st][2] = faB[2]; kfB[st][3] = faB[3]; \
    if (DODV) { lppA -= (DTB) * dvA; lppB -= (DTB) * dvB; } }

    for (int step = 0; step < 8; ++step) {
        const float t0 = dt * (float)step;
        STAGE(0, 0.f,     dt*(35.f/384.f),    1, S0X)
        STAGE(1, 0.2f,    0.f,                0, S1X)
        STAGE(2, 0.3f,    dt*(500.f/1113.f),  1, S2X)
        STAGE(3, 0.8f,    dt*(125.f/192.f),   1, S3X)
        STAGE(4, 8.f/9.f, dt*(-2187.f/6784.f),1, S4X)
        STAGE(5, 1.f,     dt*(11.f/84.f),     1, S5X)
        zvA[0] += dt * CBX(kfA,0);  zvA[1] += dt * CBX(kfA,1);
        zvA[2] += dt * CBX(kfA,2);  zvA[3] += dt * CBX(kfA,3);
        zvB[0] += dt * CBX(kfB,0);  zvB[1] += dt * CBX(kfB,1);
        zvB[2] += dt * CBX(kfB,2);  zvB[3] += dt * CBX(kfB,3);
    }

    // ---------------- epilogue ----------------
    *(f32x4*)(Og + rowA * 64 + colb + quad * 4) = zvA;
    *(f32x4*)(Og + rowB * 64 + colb + quad * 4) = zvB;
    float ssA = zvA[0]*zvA[0] + zvA[1]*zvA[1] + zvA[2]*zvA[2] + zvA[3]*zvA[3];
    float ssB = zvB[0]*zvB[0] + zvB[1]*zvB[1] + zvB[2]*zvB[2] + zvB[3]*zvB[3];
    ssA += __shfl_xor(ssA, 16);  ssA += __shfl_xor(ssA, 32);
    ssB += __shfl_xor(ssB, 16);  ssB += __shfl_xor(ssB, 32);
    float lpA = lppA;  lpA += __shfl_xor(lpA, 16);  lpA += __shfl_xor(lpA, 32);
    float lpB = lppB;  lpB += __shfl_xor(lpB, 16);  lpB += __shfl_xor(lpB, 32);
    if (quad == 0) {
        sRedSS[wave * 16 + l16] = ssA;       sRedLP[wave * 16 + l16] = lpA;
        sRedSS[64 + wave * 16 + l16] = ssB;  sRedLP[64 + wave * 16 + l16] = lpB;
    }
    __syncthreads();
    if (tid < 32) {
        const float CLOG = -58.8120661f;  // -32*ln(2*pi)
        int half = tid >> 4, r = tid & 15, base = half * 64;
        float sfull = sRedSS[base + r] + sRedSS[base + 16 + r]
                    + sRedSS[base + 32 + r] + sRedSS[base + 48 + r];
        float lfull = sRedLP[base + r] + sRedLP[base + 16 + r]
                    + sRedLP[base + 32 + r] + sRedLP[base + 48 + r];
        Og[32768 * 64 + blockIdx.x * 32 + half * 16 + r] = CLOG - 0.5f * sfull - lfull;
    }
}

extern "C" void kernel_launch(void* const* d_in, const int* in_sizes, int n_in,
                              void* d_out, int out_size, void* d_ws, size_t ws_size,
                              hipStream_t stream) {
    const float* Yg  = (const float*)d_in[0];
    const float* Eg  = (const float*)d_in[1];
    const float* W1g = (const float*)d_in[2];  // [65][256]
    const float* b1g = (const float*)d_in[3];
    const float* W2g = (const float*)d_in[4];  // [256][64]
    const float* b2g = (const float*)d_in[5];
    float* Og = (float*)d_out;                 // z (32768*64) then log_px (32768)
    cnf_kernel<<<dim3(1024), dim3(256), 0, stream>>>(Yg, Eg, W1g, b1g, W2g, b2g, Og);
}

// Round 12
// 249.559 us; speedup vs baseline: 2.1288x; 1.0803x over previous
//
#include <hip/hip_runtime.h>

// CNF forward: 8 fixed dopri5 steps x 6 stages, rows independent.
// R17: R16 = 234us steady, VALU 57 / MFMA 19 / bank-conflict cycles = 16%
// of wall (92K cyc/CU). Two targeted fixes:
//  * LDS stride repair: sY 72->76 bf16 (38 dwords == 6 mod 32), sH 264->268
//    (134 dwords == 6 mod 32). Old strides were ==4 mod 32 -> lane l16 and
//    l16+8 hit identical 4-bank windows (~6-way pile-ups on sY b128 reads).
//    gcd(6,32)=2 gives all 16 l16 values distinct bank offsets.
//  * W1a/b1/W1t pre-scaled by 2*log2(e) at load: tanh input becomes the raw
//    v_exp (exp2) argument -- kills the leading v_mul in all 32 tanh/stage
//    (fast_tanh2 = exp2, add, rcp, fma). Jacobian path compensated exactly:
//    ghf *= ln2/2 (v = e@W1a_scaled is s*(e@W1a)).
// Tripwire: FETCH > 100 MB = spill -> revert to R16.

typedef __bf16 bf16x8 __attribute__((ext_vector_type(8)));
typedef __bf16 bf16x4 __attribute__((ext_vector_type(4)));
typedef float  f32x4  __attribute__((ext_vector_type(4)));
typedef unsigned int u32;

#define MFMA16(a, b, c) __builtin_amdgcn_mfma_f32_16x16x32_bf16((a), (b), (c), 0, 0, 0)

#define SY_S 76    // sY row stride in bf16 (38 dwords == 6 mod 32)
#define SH_S 268   // sH row stride in bf16 (134 dwords == 6 mod 32)

__device__ __forceinline__ float fast_tanh2(float x2) {   // x2 = 2*log2e*x
    float e = __builtin_amdgcn_exp2f(x2);                 // e^(2x)
    return 1.0f - 2.0f * __builtin_amdgcn_rcpf(e + 1.0f);
}
__device__ __forceinline__ bf16x8 cvt8(f32x4 a, f32x4 b) {
    bf16x8 r;
#pragma unroll
    for (int i = 0; i < 4; ++i) { r[i] = (__bf16)a[i]; r[4 + i] = (__bf16)b[i]; }
    return r;
}

extern "C" __global__ void __launch_bounds__(256, 2)
cnf_kernel(const float* __restrict__ Yg, const float* __restrict__ Eg,
           const float* __restrict__ W1g, const float* __restrict__ b1g,
           const float* __restrict__ W2g, const float* __restrict__ b2g,
           float* __restrict__ Og)
{
    // ---- LDS (~24 KB; 2 blocks/CU at 2 waves/EU) ----
    __shared__ __align__(16) __bf16 sYA[16 * SY_S], sYB[16 * SY_S];
    __shared__ __align__(16) __bf16 sHA[16 * SH_S], sHB[16 * SH_S];
    __shared__ float sBW[256];                      // per-stage (b1 + t*W1_t) * 2log2e
    __shared__ float sRedSS[128], sRedLP[128];

    const int tid  = threadIdx.x;
    const int wave = tid >> 6;        // 0..3
    const int lane = tid & 63;
    const int quad = lane >> 4;
    const int l16  = lane & 15;
    const int colb = wave * 16;       // own output-col tile base
    const int jb   = wave * 64;       // own hidden-j base
    const int rowA = blockIdx.x * 32 + l16;   // tile A batch row
    const int rowB = rowA + 16;               // tile B batch row

    const float TS  = 2.885390081777927f;    // 2*log2(e)
    const float IVS = 0.346573590279973f;    // ln(2)/2 = 1/TS

    // ---------------- e fragments (both tiles) ----------------
    bf16x8 aeA0, aeA1, aeB0, aeB1;
    {
        const float* eA = Eg + rowA * 64;
        const float* eB = Eg + rowB * 64;
        aeA0 = cvt8(*(const f32x4*)(eA + quad * 8),      *(const f32x4*)(eA + quad * 8 + 4));
        aeA1 = cvt8(*(const f32x4*)(eA + 32 + quad * 8), *(const f32x4*)(eA + 32 + quad * 8 + 4));
        aeB0 = cvt8(*(const f32x4*)(eB + quad * 8),      *(const f32x4*)(eB + quad * 8 + 4));
        aeB1 = cvt8(*(const f32x4*)(eB + 32 + quad * 8), *(const f32x4*)(eB + 32 + quad * 8 + 4));
    }

    // ---------------- W1 fragments, PRE-SCALED by TS (A-op: [m=j][k=d]) ----
    bf16x8 w1f[8];
#pragma unroll
    for (int t = 0; t < 4; ++t) {
#pragma unroll
        for (int h = 0; h < 2; ++h) {
            const float* src = W1g + (h * 32 + quad * 8) * 256 + jb + t * 16 + l16;
            bf16x8 f;
#pragma unroll
            for (int i = 0; i < 8; ++i) f[i] = (__bf16)(src[i * 256] * TS);
            w1f[t * 2 + h] = f;
        }
    }

    // ---------------- ghf per tile: (gh0 .* v) f32 * IVS (undo W1 scale) ----
    // v^T = (e@W1a_scaled)^T via operand swap = TS*(e@W1a)^T
    float ghfA[16], ghfB[16];
#pragma unroll
    for (int t = 0; t < 4; ++t) {
        const float* wr = W2g + (jb + t * 16 + l16) * 64;
        bf16x8 aw0 = cvt8(*(const f32x4*)(wr + quad * 8),      *(const f32x4*)(wr + quad * 8 + 4));
        bf16x8 aw1 = cvt8(*(const f32x4*)(wr + 32 + quad * 8), *(const f32x4*)(wr + 32 + quad * 8 + 4));
        f32x4 vA = {0.f,0.f,0.f,0.f}, vB = {0.f,0.f,0.f,0.f};
        f32x4 gA = {0.f,0.f,0.f,0.f}, gB = {0.f,0.f,0.f,0.f};
        vA = MFMA16(w1f[t * 2 + 0], aeA0, vA);  vA = MFMA16(w1f[t * 2 + 1], aeA1, vA);
        vB = MFMA16(w1f[t * 2 + 0], aeB0, vB);  vB = MFMA16(w1f[t * 2 + 1], aeB1, vB);
        gA = MFMA16(aw0, aeA0, gA);             gA = MFMA16(aw1, aeA1, gA);
        gB = MFMA16(aw0, aeB0, gB);             gB = MFMA16(aw1, aeB1, gB);
#pragma unroll
        for (int i = 0; i < 4; ++i) {
            ghfA[t * 4 + i] = gA[i] * vA[i] * IVS;
            ghfB[t * 4 + i] = gB[i] * vB[i] * IVS;
        }
    }

    // ---------------- W2^T fragments direct from global (A-op: [m=dout][k=j]) ----
    bf16x8 w2f[8];
#pragma unroll
    for (int c = 0; c < 8; ++c) {
        const float* src = W2g + (c * 32 + quad * 8) * 64 + colb + l16;
        bf16x8 f;
#pragma unroll
        for (int i = 0; i < 8; ++i) f[i] = (__bf16)src[i * 64];
        w2f[c] = f;
    }

    // ---------------- state (lane layout: batch=l16, d=colb+quad*4+rg) ----
    f32x4 zvA = *(const f32x4*)(Yg + rowA * 64 + colb + quad * 4);
    f32x4 zvB = *(const f32x4*)(Yg + rowB * 64 + colb + quad * 4);
    f32x4 bb2 = *(const f32x4*)(b2g + colb + quad * 4);
    const float b1r  = b1g[tid] * TS;              // own j = tid (pre-scaled)
    const float w1tr = W1g[64 * 256 + tid] * TS;   // W1 time row (pre-scaled)

    const float dt = 0.125f;
    float kfA[6][4], kfB[6][4];   // k_dz in raw f32
    float lppA = 0.f, lppB = 0.f;

#define S0X(arr, g) 0.f
#define S1X(arr, g) (0.2f*arr[0][g])
#define S2X(arr, g) (0.075f*arr[0][g] + 0.225f*arr[1][g])
#define S3X(arr, g) ((44.f/45.f)*arr[0][g] + (-56.f/15.f)*arr[1][g] + (32.f/9.f)*arr[2][g])
#define S4X(arr, g) ((19372.f/6561.f)*arr[0][g] + (-25360.f/2187.f)*arr[1][g] + \
                     (64448.f/6561.f)*arr[2][g] + (-212.f/729.f)*arr[3][g])
#define S5X(arr, g) ((9017.f/3168.f)*arr[0][g] + (-355.f/33.f)*arr[1][g] + \
                     (46732.f/5247.f)*arr[2][g] + (49.f/176.f)*arr[3][g] + \
                     (-5103.f/18656.f)*arr[4][g])
#define CBX(arr, g) ((35.f/384.f)*arr[0][g] + (500.f/1113.f)*arr[2][g] + \
                     (125.f/192.f)*arr[3][g] + (-2187.f/6784.f)*arr[4][g] + \
                     (11.f/84.f)*arr[5][g])

    // matmul-1 tile (per data-tile S, j-tile t); ua is pre-scaled by TS
#define MM1T(S, t, DODV) { \
    f32x4 ua = *(const f32x4*)(sBW + jb + (t)*16 + quad * 4); \
    ua = MFMA16(w1f[(t)*2 + 0], a10##S, ua); \
    ua = MFMA16(w1f[(t)*2 + 1], a11##S, ua); \
    float h0 = fast_tanh2(ua[0]), h1 = fast_tanh2(ua[1]); \
    float h2 = fast_tanh2(ua[2]), h3 = fast_tanh2(ua[3]); \
    if (DODV) { \
        dv##S += ghf##S[(t)*4 + 0] * (1.f - h0*h0); \
        dv##S += ghf##S[(t)*4 + 1] * (1.f - h1*h1); \
        dv##S += ghf##S[(t)*4 + 2] * (1.f - h2*h2); \
        dv##S += ghf##S[(t)*4 + 3] * (1.f - h3*h3); \
    } \
    bf16x4 hv; hv[0]=(__bf16)h0; hv[1]=(__bf16)h1; hv[2]=(__bf16)h2; hv[3]=(__bf16)h3; \
    *(bf16x4*)(sH##S + l16 * SH_S + jb + (t)*16 + quad * 4) = hv; }

#define MM2C(S, c, acc) { \
    bf16x8 hf = *(const bf16x8*)(sH##S + l16 * SH_S + (c)*32 + quad * 8); \
    acc = MFMA16(w2f[c], hf, acc); }

#define STAGE(st, CTI, DTB, DODV, SX) { \
    const float ti = t0 + (CTI) * dt; \
    { bf16x4 yv; \
      yv[0] = (__bf16)(zvA[0] + dt * (SX(kfA,0))); \
      yv[1] = (__bf16)(zvA[1] + dt * (SX(kfA,1))); \
      yv[2] = (__bf16)(zvA[2] + dt * (SX(kfA,2))); \
      yv[3] = (__bf16)(zvA[3] + dt * (SX(kfA,3))); \
      *(bf16x4*)(sYA + l16 * SY_S + colb + quad * 4) = yv; } \
    { bf16x4 yv; \
      yv[0] = (__bf16)(zvB[0] + dt * (SX(kfB,0))); \
      yv[1] = (__bf16)(zvB[1] + dt * (SX(kfB,1))); \
      yv[2] = (__bf16)(zvB[2] + dt * (SX(kfB,2))); \
      yv[3] = (__bf16)(zvB[3] + dt * (SX(kfB,3))); \
      *(bf16x4*)(sYB + l16 * SY_S + colb + quad * 4) = yv; } \
    sBW[tid] = b1r + ti * w1tr; \
    __syncthreads();  /* barrier1: sY/sBW */ \
    bf16x8 a10A = *(const bf16x8*)(sYA + l16 * SY_S + quad * 8); \
    bf16x8 a11A = *(const bf16x8*)(sYA + l16 * SY_S + 32 + quad * 8); \
    bf16x8 a10B = *(const bf16x8*)(sYB + l16 * SY_S + quad * 8); \
    bf16x8 a11B = *(const bf16x8*)(sYB + l16 * SY_S + 32 + quad * 8); \
    float dvA = 0.f, dvB = 0.f; \
    MM1T(A,0,DODV) MM1T(B,0,DODV) MM1T(A,1,DODV) MM1T(B,1,DODV) \
    MM1T(A,2,DODV) MM1T(B,2,DODV) MM1T(A,3,DODV) MM1T(B,3,DODV) \
    __syncthreads();  /* barrier2: sH */ \
    f32x4 faA0 = bb2, faA1 = {0.f,0.f,0.f,0.f}; \
    f32x4 faB0 = bb2, faB1 = {0.f,0.f,0.f,0.f}; \
    MM2C(A,0,faA0) MM2C(B,0,faB0) MM2C(A,1,faA1) MM2C(B,1,faB1) \
    MM2C(A,2,faA0) MM2C(B,2,faB0) MM2C(A,3,faA1) MM2C(B,3,faB1) \
    MM2C(A,4,faA0) MM2C(B,4,faB0) MM2C(A,5,faA1) MM2C(B,5,faB1) \
    MM2C(A,6,faA0) MM2C(B,6,faB0) MM2C(A,7,faA1) MM2C(B,7,faB1) \
    f32x4 faA = faA0 + faA1, faB = faB0 + faB1; \
    kfA[st][0] = faA[0]; kfA[st][1] = faA[1]; kfA[st][2] = faA[2]; kfA[st][3] = faA[3]; \
    kfB[st][0] = faB[0]; kfB[st][1] = faB[1]; kfB[st][2] = faB[2]; kfB[st][3] = faB[3]; \
    if (DODV) { lppA -= (DTB) * dvA; lppB -= (DTB) * dvB; } }

    for (int step = 0; step < 8; ++step) {
        const float t0 = dt * (float)step;
        STAGE(0, 0.f,     dt*(35.f/384.f),    1, S0X)
        STAGE(1, 0.2f,    0.f,                0, S1X)
        STAGE(2, 0.3f,    dt*(500.f/1113.f),  1, S2X)
        STAGE(3, 0.8f,    dt*(125.f/192.f),   1, S3X)
        STAGE(4, 8.f/9.f, dt*(-2187.f/6784.f),1, S4X)
        STAGE(5, 1.f,     dt*(11.f/84.f),     1, S5X)
        zvA[0] += dt * CBX(kfA,0);  zvA[1] += dt * CBX(kfA,1);
        zvA[2] += dt * CBX(kfA,2);  zvA[3] += dt * CBX(kfA,3);
        zvB[0] += dt * CBX(kfB,0);  zvB[1] += dt * CBX(kfB,1);
        zvB[2] += dt * CBX(kfB,2);  zvB[3] += dt * CBX(kfB,3);
    }

    // ---------------- epilogue ----------------
    *(f32x4*)(Og + rowA * 64 + colb + quad * 4) = zvA;
    *(f32x4*)(Og + rowB * 64 + colb + quad * 4) = zvB;
    float ssA = zvA[0]*zvA[0] + zvA[1]*zvA[1] + zvA[2]*zvA[2] + zvA[3]*zvA[3];
    float ssB = zvB[0]*zvB[0] + zvB[1]*zvB[1] + zvB[2]*zvB[2] + zvB[3]*zvB[3];
    ssA += __shfl_xor(ssA, 16);  ssA += __shfl_xor(ssA, 32);
    ssB += __shfl_xor(ssB, 16);  ssB += __shfl_xor(ssB, 32);
    float lpA = lppA;  lpA += __shfl_xor(lpA, 16);  lpA += __shfl_xor(lpA, 32);
    float lpB = lppB;  lpB += __shfl_xor(lpB, 16);  lpB += __shfl_xor(lpB, 32);
    if (quad == 0) {
        sRedSS[wave * 16 + l16] = ssA;       sRedLP[wave * 16 + l16] = lpA;
        sRedSS[64 + wave * 16 + l16] = ssB;  sRedLP[64 + wave * 16 + l16] = lpB;
    }
    __syncthreads();
    if (tid < 32) {
        const float CLOG = -58.8120661f;  // -32*ln(2*pi)
        int half = tid >> 4, r = tid & 15, base = half * 64;
        float sfull = sRedSS[base + r] + sRedSS[base + 16 + r]
                    + sRedSS[base + 32 + r] + sRedSS[base + 48 + r];
        float lfull = sRedLP[base + r] + sRedLP[base + 16 + r]
                    + sRedLP[base + 32 + r] + sRedLP[base + 48 + r];
        Og[32768 * 64 + blockIdx.x * 32 + half * 16 + r] = CLOG - 0.5f * sfull - lfull;
    }
}

extern "C" void kernel_launch(void* const* d_in, const int* in_sizes, int n_in,
                              void* d_out, int out_size, void* d_ws, size_t ws_size,
                              hipStream_t stream) {
    const float* Yg  = (const float*)d_in[0];
    const float* Eg  = (const float*)d_in[1];
    const float* W1g = (const float*)d_in[2];  // [65][256]
    const float* b1g = (const float*)d_in[3];
    const float* W2g = (const float*)d_in[4];  // [256][64]
    const float* b2g = (const float*)d_in[5];
    float* Og = (float*)d_out;                 // z (32768*64) then log_px (32768)
    cnf_kernel<<<dim3(1024), dim3(256), 0, stream>>>(Yg, Eg, W1g, b1g, W2g, b2g, Og);
}